// Round 1
// 2002.592 us; speedup vs baseline: 1.2915x; 1.2915x over previous
//
#include <hip/hip_runtime.h>
#include <cstddef>

typedef __bf16 bf16;
typedef bf16 bf16x4 __attribute__((ext_vector_type(4)));
typedef bf16 bf16x8 __attribute__((ext_vector_type(8)));
typedef float f32x4 __attribute__((ext_vector_type(4)));

#define N_NODES 50000
#define N_EDGES 800000
#define HID 128
#define NF 128
#define EC 100
#define NBLK 6
#define IN_DIM 5
#define LN2 0.69314718055994530942f
#define LDST 136          // bf16 LDS stride: 128 + 8 pad (16B-aligned rows, bank-skewed)
#define MST 136           // fp32 msg stride
#define EAS 112           // bf16 stride of pre-permuted edge_attr (cols 100..111 zero)
#define FRAG_ELEMS 16384  // one repacked 128x128 weight: 2048 frags x 8 bf16
#define HIST_PAD 50176    // 50000 rounded to 256*196, float4-zeroable

__device__ __forceinline__ float ssp_f(float v) {
  float e = __expf(-fabsf(v));
  return fmaxf(v, 0.0f) + __logf(1.0f + e) - LN2;
}

__device__ __forceinline__ f32x4 zero4() {
  f32x4 v; v[0] = 0.f; v[1] = 0.f; v[2] = 0.f; v[3] = 0.f; return v;
}

// ---------------- weight repack (once per launch) ----------------
__global__ void repack_kernel(const float* __restrict__ src, bf16* __restrict__ dst,
                              int K, int srcStride) {
  const int m = blockIdx.x;
  const float* s = src + (size_t)m * srcStride;
  bf16* d = dst + (size_t)m * FRAG_ELEMS;
  const int tid = threadIdx.x;
  const int wave = tid >> 6, lane = tid & 63;
  const int quad = lane >> 4, lanelo = lane & 15;
  const int col = wave * 32 + lanelo;
#pragma unroll
  for (int nt = 0; nt < 2; nt++)
#pragma unroll
    for (int ks = 0; ks < 4; ks++) {
      bf16x8 f;
#pragma unroll
      for (int j = 0; j < 8; j++) {
        int k = ks * 32 + quad * 8 + j;
        f[j] = (bf16)((k < K) ? s[(size_t)k * 128 + col + nt * 16] : 0.0f);
      }
      *(bf16x8*)&d[(size_t)(((wave * 2 + nt) * 4 + ks) * 64 + lane) * 8] = f;
    }
}

// ---------------- counting sort of VALID edges by dst (once per launch) ----------------
__global__ void hist_kernel(const int* __restrict__ ei, const float* __restrict__ elen,
                            int* __restrict__ hist, int* __restrict__ nvalid) {
  int e = blockIdx.x * 256 + threadIdx.x;
  if (e < N_EDGES) {
    float L = elen[e];
    if (L <= 10.0f && L >= 0.0f) {
      atomicAdd(&hist[ei[N_EDGES + e]], 1);
      atomicAdd(nvalid, 1);   // wave-coalesced by compiler
    }
  }
}

__global__ void scan_blocks_kernel(const int* __restrict__ in, int* __restrict__ out,
                                   int* __restrict__ bsums) {
  __shared__ int s[256];
  int i = blockIdx.x * 256 + threadIdx.x;
  int v = in[i];
  s[threadIdx.x] = v;
  __syncthreads();
#pragma unroll
  for (int off = 1; off < 256; off <<= 1) {
    int t = (threadIdx.x >= off) ? s[threadIdx.x - off] : 0;
    __syncthreads();
    s[threadIdx.x] += t;
    __syncthreads();
  }
  out[i] = s[threadIdx.x] - v;
  if (threadIdx.x == 255) bsums[blockIdx.x] = s[255];
}

__global__ void scan_bsums_kernel(int* __restrict__ bsums, int nb) {
  __shared__ int s[256];
  int v = (threadIdx.x < nb) ? bsums[threadIdx.x] : 0;
  s[threadIdx.x] = v;
  __syncthreads();
#pragma unroll
  for (int off = 1; off < 256; off <<= 1) {
    int t = (threadIdx.x >= off) ? s[threadIdx.x - off] : 0;
    __syncthreads();
    s[threadIdx.x] += t;
    __syncthreads();
  }
  if (threadIdx.x < nb) bsums[threadIdx.x] = s[threadIdx.x] - v;
}

__global__ void scan_add_kernel(int* __restrict__ out, const int* __restrict__ bsums,
                                int* __restrict__ cursor) {
  int i = blockIdx.x * 256 + threadIdx.x;
  int v = out[i] + bsums[blockIdx.x];
  out[i] = v;
  cursor[i] = v;
}

// scatter valid edges only; also pack sorted (src,dst) metadata
__global__ void scatter_kernel(const int* __restrict__ ei, const float* __restrict__ elen,
                               int* __restrict__ cursor, int* __restrict__ perm,
                               int2* __restrict__ einfo) {
  int e = blockIdx.x * 256 + threadIdx.x;
  if (e < N_EDGES) {
    float L = elen[e];
    if (L <= 10.0f && L >= 0.0f) {
      int s = ei[e];
      int d = ei[N_EDGES + e];
      int pos = atomicAdd(&cursor[d], 1);
      perm[pos] = e;
      einfo[pos] = make_int2(s, d);
    }
  }
}

// ---------------- pre-permute edge_attr into sorted bf16 stream (once per launch) ----------
// eas[pos][0..99] = bf16(ea[perm[pos]][0..99]); cols 100..111 = 0. Rows >= nvalid in the
// last partial tile are zero-filled so edge_kernel can read the tile unconditionally.
__global__ void permute_ea_kernel(const float* __restrict__ ea,
                                  const int* __restrict__ perm,
                                  const int* __restrict__ nvalid,
                                  bf16* __restrict__ eas) {
  const int nv = *nvalid;
  const int e0 = blockIdx.x * 64;
  if (e0 >= nv) return;
  const int tid = threadIdx.x;
#pragma unroll
  for (int it = 0; it < 4; it++) {
    int u = tid + it * 256;
    if (u < 64 * 14) {
      int r = u / 14, s = u - r * 14;
      int row = e0 + r;
      bf16x8 o;
#pragma unroll
      for (int j = 0; j < 8; j++) o[j] = (bf16)0.0f;
      if (row < nv) {
        int pe = perm[row];
        const float* src = ea + (size_t)pe * EC;
        if (s < 12) {
          float4 a = *(const float4*)&src[s * 8];
          float4 b = *(const float4*)&src[s * 8 + 4];
          o[0] = (bf16)a.x; o[1] = (bf16)a.y; o[2] = (bf16)a.z; o[3] = (bf16)a.w;
          o[4] = (bf16)b.x; o[5] = (bf16)b.y; o[6] = (bf16)b.z; o[7] = (bf16)b.w;
        } else if (s == 12) {
          float4 a = *(const float4*)&src[96];
          o[0] = (bf16)a.x; o[1] = (bf16)a.y; o[2] = (bf16)a.z; o[3] = (bf16)a.w;
        }
      }
      *(bf16x8*)&eas[(size_t)row * EAS + s * 8] = o;
    }
  }
}

// ---------------- misc ----------------
__global__ void embed_kernel(const float* __restrict__ z,
                             const float* __restrict__ ew,
                             const float* __restrict__ eb,
                             float* __restrict__ h) {
  int i = blockIdx.x * 256 + threadIdx.x;
  if (i >= N_NODES * HID) return;
  int n = i >> 7, c = i & 127;
  const float* zr = z + (size_t)n * (IN_DIM + HID);
  float acc = eb[c] + zr[IN_DIM + c];
#pragma unroll
  for (int k = 0; k < IN_DIM; k++) acc = fmaf(zr[k], ew[k * HID + c], acc);
  h[i] = acc;
}

__global__ void zero_kernel(float4* __restrict__ p, int n4) {
  int i = blockIdx.x * 256 + threadIdx.x;
  if (i < n4) p[i] = make_float4(0.f, 0.f, 0.f, 0.f);
}

// ---------------- x = h @ w (block 0 only; later blocks fused into node_kernel) --------
__global__ __launch_bounds__(256, 4)
void xgemm_kernel(const float* __restrict__ hmat,
                  const bf16* __restrict__ wf,
                  float* __restrict__ xout) {
  __shared__ bf16 sA[64 * LDST];
  const int tid = threadIdx.x;
  const int wave = tid >> 6, lane = tid & 63;
  const int quad = lane >> 4, lanelo = lane & 15;
  const int ncol0 = wave * 32;
  const int row0 = blockIdx.x * 64;

  bf16x8 Bf[2][4];
#pragma unroll
  for (int nt = 0; nt < 2; nt++)
#pragma unroll
    for (int ks = 0; ks < 4; ks++)
      Bf[nt][ks] = *(const bf16x8*)&wf[(size_t)(((wave * 2 + nt) * 4 + ks) * 64 + lane) * 8];

#pragma unroll
  for (int it = 0; it < 8; it++) {
    int idx = tid + it * 256;
    int r = idx >> 5, c4 = idx & 31;
    int grow = row0 + r;
    float4 v = (grow < N_NODES) ? *(const float4*)&hmat[(size_t)grow * HID + c4 * 4]
                                : make_float4(0.f, 0.f, 0.f, 0.f);
    bf16x4 o; o[0] = (bf16)v.x; o[1] = (bf16)v.y; o[2] = (bf16)v.z; o[3] = (bf16)v.w;
    *(bf16x4*)&sA[r * LDST + c4 * 4] = o;
  }
  __syncthreads();

  f32x4 acc[4][2];
#pragma unroll
  for (int mt = 0; mt < 4; mt++)
#pragma unroll
    for (int nt = 0; nt < 2; nt++) acc[mt][nt] = zero4();
#pragma unroll
  for (int ks = 0; ks < 4; ks++) {
    bf16x8 a[4];
#pragma unroll
    for (int mt = 0; mt < 4; mt++)
      a[mt] = *(const bf16x8*)&sA[(mt * 16 + lanelo) * LDST + ks * 32 + quad * 8];
#pragma unroll
    for (int mt = 0; mt < 4; mt++)
#pragma unroll
      for (int nt = 0; nt < 2; nt++)
        acc[mt][nt] = __builtin_amdgcn_mfma_f32_16x16x32_bf16(a[mt], Bf[nt][ks], acc[mt][nt], 0, 0, 0);
  }
#pragma unroll
  for (int mt = 0; mt < 4; mt++)
#pragma unroll
    for (int r = 0; r < 4; r++) {
      int grow = row0 + mt * 16 + quad * 4 + r;
      if (grow < N_NODES) {
#pragma unroll
        for (int nt = 0; nt < 2; nt++)
          xout[(size_t)grow * NF + ncol0 + nt * 16 + lanelo] = acc[mt][nt][r];
      }
    }
}

// ---------------- fused edge MLP + gather + segmented scatter-reduce ----------------
// ea pre-permuted+bf16 -> staging is a coalesced stream; only valid (C=1) edges present.
__global__ __launch_bounds__(256, 4)
void edge_kernel(const bf16* __restrict__ eas,
                 const int2* __restrict__ einfo,
                 const int* __restrict__ nvalid,
                 const bf16* __restrict__ w1f, const float* __restrict__ b1,
                 const bf16* __restrict__ w2f, const float* __restrict__ b2,
                 const float* __restrict__ x,
                 float* __restrict__ agg) {
  __shared__ alignas(16) char s_buf[64 * MST * 4];  // 34816 B (bf16 GEMM tile / fp32 msg alias)
  bf16* sA = (bf16*)s_buf;
  float* s_msg = (float*)s_buf;
  __shared__ int s_src[64];
  __shared__ int s_dst[64];

  const int nv = *nvalid;
  const int e0 = blockIdx.x * 64;
  if (e0 >= nv) return;

  const int tid = threadIdx.x;
  const int wave = tid >> 6, lane = tid & 63;
  const int quad = lane >> 4, lanelo = lane & 15;
  const int ncol0 = wave * 32;

  bf16x8 Bf1[2][4], Bf2[2][4];
#pragma unroll
  for (int nt = 0; nt < 2; nt++)
#pragma unroll
    for (int ks = 0; ks < 4; ks++) {
      size_t fo = (size_t)(((wave * 2 + nt) * 4 + ks) * 64 + lane) * 8;
      Bf1[nt][ks] = *(const bf16x8*)&w1f[fo];
      Bf2[nt][ks] = *(const bf16x8*)&w2f[fo];
    }
  float bias1[2], bias2[2];
#pragma unroll
  for (int nt = 0; nt < 2; nt++) {
    bias1[nt] = b1[ncol0 + nt * 16 + lanelo];
    bias2[nt] = b2[ncol0 + nt * 16 + lanelo];
  }

  // stage sorted ea tile: 64 rows x 17 segs of 8 bf16 (segs 0..13 from stream, 14..16 zero)
#pragma unroll
  for (int it = 0; it < 5; it++) {
    int u = tid + it * 256;
    if (u < 64 * 17) {
      int r = u / 17, s = u - r * 17;
      bf16x8 o;
      if (s < 14) {
        o = *(const bf16x8*)&eas[(size_t)(e0 + r) * EAS + s * 8];
      } else {
#pragma unroll
        for (int j = 0; j < 8; j++) o[j] = (bf16)0.0f;
      }
      *(bf16x8*)&sA[r * LDST + s * 8] = o;
    }
  }
  if (tid < 64) {
    int2 sd = einfo[e0 + tid];   // tail rows: (0,0) from prefill -> contribute exact 0
    s_src[tid] = sd.x;
    s_dst[tid] = sd.y;
  }
  __syncthreads();

  // GEMM1: t = ea @ w1
  f32x4 acc[4][2];
#pragma unroll
  for (int mt = 0; mt < 4; mt++)
#pragma unroll
    for (int nt = 0; nt < 2; nt++) acc[mt][nt] = zero4();
#pragma unroll
  for (int ks = 0; ks < 4; ks++) {
    bf16x8 a[4];
#pragma unroll
    for (int mt = 0; mt < 4; mt++)
      a[mt] = *(const bf16x8*)&sA[(mt * 16 + lanelo) * LDST + ks * 32 + quad * 8];
#pragma unroll
    for (int mt = 0; mt < 4; mt++)
#pragma unroll
      for (int nt = 0; nt < 2; nt++)
        acc[mt][nt] = __builtin_amdgcn_mfma_f32_16x16x32_bf16(a[mt], Bf1[nt][ks], acc[mt][nt], 0, 0, 0);
  }
  __syncthreads();

  // ssp, C-layout -> A-layout, in place
#pragma unroll
  for (int mt = 0; mt < 4; mt++)
#pragma unroll
    for (int nt = 0; nt < 2; nt++)
#pragma unroll
      for (int r = 0; r < 4; r++) {
        float v = ssp_f(acc[mt][nt][r] + bias1[nt]);
        sA[(mt * 16 + quad * 4 + r) * LDST + ncol0 + nt * 16 + lanelo] = (bf16)v;
      }
  __syncthreads();

  // GEMM2: W = t @ w2
#pragma unroll
  for (int mt = 0; mt < 4; mt++)
#pragma unroll
    for (int nt = 0; nt < 2; nt++) acc[mt][nt] = zero4();
#pragma unroll
  for (int ks = 0; ks < 4; ks++) {
    bf16x8 a[4];
#pragma unroll
    for (int mt = 0; mt < 4; mt++)
      a[mt] = *(const bf16x8*)&sA[(mt * 16 + lanelo) * LDST + ks * 32 + quad * 8];
#pragma unroll
    for (int mt = 0; mt < 4; mt++)
#pragma unroll
      for (int nt = 0; nt < 2; nt++)
        acc[mt][nt] = __builtin_amdgcn_mfma_f32_16x16x32_bf16(a[mt], Bf2[nt][ks], acc[mt][nt], 0, 0, 0);
  }
  __syncthreads();  // all waves done with sA before fp32 msg overwrite (aliased)

  // msg = x[src] * W -> LDS (fp32); tile-tail rows write 0 and skip the gather
#pragma unroll
  for (int mt = 0; mt < 4; mt++)
#pragma unroll
    for (int r = 0; r < 4; r++) {
      int row = mt * 16 + quad * 4 + r;
      bool valid = (e0 + row < nv);
      int srcn = s_src[row];
#pragma unroll
      for (int nt = 0; nt < 2; nt++) {
        int col = ncol0 + nt * 16 + lanelo;
        float g = valid ? x[(size_t)srcn * NF + col] : 0.0f;
        float wv = acc[mt][nt][r] + bias2[nt];
        s_msg[row * MST + col] = valid ? wv * g : 0.0f;
      }
    }
  __syncthreads();

  // segmented per-column reduction over dst-sorted rows
  {
    const int col = tid & 127;
    const int r0 = (tid >> 7) * 32;
    float acc2 = 0.0f;
    int prev = s_dst[r0];
    for (int r = r0; r < r0 + 32; r++) {
      int d = s_dst[r];
      if (d != prev) {
        atomicAdd(&agg[(size_t)prev * NF + col], acc2);
        acc2 = 0.0f;
        prev = d;
      }
      acc2 += s_msg[r * MST + col];
    }
    atomicAdd(&agg[(size_t)prev * NF + col], acc2);
  }
}

// ---------------- h += ssp(agg@lin2+b)@lin+b ; optionally x_next = h_new @ lin1_next ----
__global__ __launch_bounds__(256, 4)
void node_kernel(const float* __restrict__ agg,
                 const bf16* __restrict__ w1f, const float* __restrict__ b1,
                 const bf16* __restrict__ w2f, const float* __restrict__ b2,
                 const bf16* __restrict__ wxf,   // lin1 of next block, or null
                 float* __restrict__ h,
                 float* __restrict__ x) {
  __shared__ bf16 sA[64 * LDST];
  const int tid = threadIdx.x;
  const int wave = tid >> 6, lane = tid & 63;
  const int quad = lane >> 4, lanelo = lane & 15;
  const int ncol0 = wave * 32;
  const int row0 = blockIdx.x * 64;

  bf16x8 Bf1[2][4], Bf2[2][4];
#pragma unroll
  for (int nt = 0; nt < 2; nt++)
#pragma unroll
    for (int ks = 0; ks < 4; ks++) {
      size_t fo = (size_t)(((wave * 2 + nt) * 4 + ks) * 64 + lane) * 8;
      Bf1[nt][ks] = *(const bf16x8*)&w1f[fo];
      Bf2[nt][ks] = *(const bf16x8*)&w2f[fo];
    }
  float bias1[2], bias2[2];
#pragma unroll
  for (int nt = 0; nt < 2; nt++) {
    bias1[nt] = b1[ncol0 + nt * 16 + lanelo];
    bias2[nt] = b2[ncol0 + nt * 16 + lanelo];
  }

#pragma unroll
  for (int it = 0; it < 8; it++) {
    int idx = tid + it * 256;
    int r = idx >> 5, c4 = idx & 31;
    int grow = row0 + r;
    float4 v = (grow < N_NODES) ? *(const float4*)&agg[(size_t)grow * NF + c4 * 4]
                                : make_float4(0.f, 0.f, 0.f, 0.f);
    bf16x4 o; o[0] = (bf16)v.x; o[1] = (bf16)v.y; o[2] = (bf16)v.z; o[3] = (bf16)v.w;
    *(bf16x4*)&sA[r * LDST + c4 * 4] = o;
  }
  __syncthreads();

  f32x4 acc[4][2];
#pragma unroll
  for (int mt = 0; mt < 4; mt++)
#pragma unroll
    for (int nt = 0; nt < 2; nt++) acc[mt][nt] = zero4();
#pragma unroll
  for (int ks = 0; ks < 4; ks++) {
    bf16x8 a[4];
#pragma unroll
    for (int mt = 0; mt < 4; mt++)
      a[mt] = *(const bf16x8*)&sA[(mt * 16 + lanelo) * LDST + ks * 32 + quad * 8];
#pragma unroll
    for (int mt = 0; mt < 4; mt++)
#pragma unroll
      for (int nt = 0; nt < 2; nt++)
        acc[mt][nt] = __builtin_amdgcn_mfma_f32_16x16x32_bf16(a[mt], Bf1[nt][ks], acc[mt][nt], 0, 0, 0);
  }
  __syncthreads();

#pragma unroll
  for (int mt = 0; mt < 4; mt++)
#pragma unroll
    for (int nt = 0; nt < 2; nt++)
#pragma unroll
      for (int r = 0; r < 4; r++) {
        float v = ssp_f(acc[mt][nt][r] + bias1[nt]);
        sA[(mt * 16 + quad * 4 + r) * LDST + ncol0 + nt * 16 + lanelo] = (bf16)v;
      }
  __syncthreads();

#pragma unroll
  for (int mt = 0; mt < 4; mt++)
#pragma unroll
    for (int nt = 0; nt < 2; nt++) acc[mt][nt] = zero4();
#pragma unroll
  for (int ks = 0; ks < 4; ks++) {
    bf16x8 a[4];
#pragma unroll
    for (int mt = 0; mt < 4; mt++)
      a[mt] = *(const bf16x8*)&sA[(mt * 16 + lanelo) * LDST + ks * 32 + quad * 8];
#pragma unroll
    for (int mt = 0; mt < 4; mt++)
#pragma unroll
      for (int nt = 0; nt < 2; nt++)
        acc[mt][nt] = __builtin_amdgcn_mfma_f32_16x16x32_bf16(a[mt], Bf2[nt][ks], acc[mt][nt], 0, 0, 0);
  }
  __syncthreads();  // all GEMM2 LDS reads done before sA overwrite

  // h_new = h + acc + b2 -> global h; also stage h_new (bf16) for the fused x-GEMM
#pragma unroll
  for (int mt = 0; mt < 4; mt++)
#pragma unroll
    for (int nt = 0; nt < 2; nt++)
#pragma unroll
      for (int r = 0; r < 4; r++) {
        int row = mt * 16 + quad * 4 + r;
        int grow = row0 + row;
        int col = ncol0 + nt * 16 + lanelo;
        float hv = acc[mt][nt][r] + bias2[nt];
        if (grow < N_NODES) {
          size_t off = (size_t)grow * HID + col;
          hv += h[off];
          h[off] = hv;
        }
        sA[row * LDST + col] = (bf16)hv;
      }

  if (wxf != nullptr) {
    bf16x8 Bfx[2][4];
#pragma unroll
    for (int nt = 0; nt < 2; nt++)
#pragma unroll
      for (int ks = 0; ks < 4; ks++)
        Bfx[nt][ks] = *(const bf16x8*)&wxf[(size_t)(((wave * 2 + nt) * 4 + ks) * 64 + lane) * 8];
    __syncthreads();
#pragma unroll
    for (int mt = 0; mt < 4; mt++)
#pragma unroll
      for (int nt = 0; nt < 2; nt++) acc[mt][nt] = zero4();
#pragma unroll
    for (int ks = 0; ks < 4; ks++) {
      bf16x8 a[4];
#pragma unroll
      for (int mt = 0; mt < 4; mt++)
        a[mt] = *(const bf16x8*)&sA[(mt * 16 + lanelo) * LDST + ks * 32 + quad * 8];
#pragma unroll
      for (int mt = 0; mt < 4; mt++)
#pragma unroll
        for (int nt = 0; nt < 2; nt++)
          acc[mt][nt] = __builtin_amdgcn_mfma_f32_16x16x32_bf16(a[mt], Bfx[nt][ks], acc[mt][nt], 0, 0, 0);
    }
#pragma unroll
    for (int mt = 0; mt < 4; mt++)
#pragma unroll
      for (int r = 0; r < 4; r++) {
        int grow = row0 + mt * 16 + quad * 4 + r;
        if (grow < N_NODES) {
#pragma unroll
          for (int nt = 0; nt < 2; nt++)
            x[(size_t)grow * NF + ncol0 + nt * 16 + lanelo] = acc[mt][nt][r];
        }
      }
  }
}

extern "C" void kernel_launch(void* const* d_in, const int* in_sizes, int n_in,
                              void* d_out, int out_size, void* d_ws, size_t ws_size,
                              hipStream_t stream) {
  const float* z        = (const float*)d_in[0];
  const int*   ei       = (const int*)d_in[1];
  const float* elen     = (const float*)d_in[2];
  const float* ea       = (const float*)d_in[3];
  const float* emblin_w = (const float*)d_in[4];
  const float* emblin_b = (const float*)d_in[5];
  const float* lin1_w   = (const float*)d_in[6];
  const float* nn_w1    = (const float*)d_in[7];
  const float* nn_b1    = (const float*)d_in[8];
  const float* nn_w2    = (const float*)d_in[9];
  const float* nn_b2    = (const float*)d_in[10];
  const float* lin2_w   = (const float*)d_in[11];
  const float* lin2_b   = (const float*)d_in[12];
  const float* lin_w    = (const float*)d_in[13];
  const float* lin_b    = (const float*)d_in[14];

  float* h   = (float*)d_out;                        // 50000 x 128
  // ---- workspace layout (eas last; touched extent = nvalid rows) ----
  char* base = (char*)d_ws;
  float* x    = (float*)base;  base += (size_t)N_NODES * NF * 4;              // 25.6 MB
  float* agg  = (float*)base;  base += (size_t)N_NODES * NF * 4;              // 25.6 MB
  bf16* wp    = (bf16*)base;   base += (size_t)5 * NBLK * FRAG_ELEMS * 2;     // 0.98 MB
  int* hist   = (int*)base;    base += (size_t)HIST_PAD * 4;
  int* cursor = (int*)base;    base += (size_t)HIST_PAD * 4;
  int* bsums  = (int*)base;    base += 1024;
  int* nvalid = (int*)base;    base += 16;
  int* perm   = (int*)base;    base += (size_t)N_EDGES * 4;                   // 3.2 MB
  int2* einfo = (int2*)base;   base += (size_t)N_EDGES * 8;                   // 6.4 MB
  bf16* eas   = (bf16*)base;   base += (size_t)N_EDGES * EAS * 2;             // 179.2 MB

  bf16* wp_lin1 = wp;
  bf16* wp_nw1  = wp + 1 * (size_t)NBLK * FRAG_ELEMS;
  bf16* wp_nw2  = wp + 2 * (size_t)NBLK * FRAG_ELEMS;
  bf16* wp_l2   = wp + 3 * (size_t)NBLK * FRAG_ELEMS;
  bf16* wp_l    = wp + 4 * (size_t)NBLK * FRAG_ELEMS;

  // weight repack
  repack_kernel<<<NBLK, 256, 0, stream>>>(lin1_w, wp_lin1, HID, HID * NF);
  repack_kernel<<<NBLK, 256, 0, stream>>>(nn_w1, wp_nw1, EC, EC * NF);
  repack_kernel<<<NBLK, 256, 0, stream>>>(nn_w2, wp_nw2, NF, NF * NF);
  repack_kernel<<<NBLK, 256, 0, stream>>>(lin2_w, wp_l2, NF, NF * HID);
  repack_kernel<<<NBLK, 256, 0, stream>>>(lin_w, wp_l, HID, HID * HID);

  // counting sort of VALID edges by dst + sorted metadata + sorted bf16 edge_attr
  const int nb = HIST_PAD / 256;  // 196
  zero_kernel<<<(HIST_PAD / 4 + 255) / 256, 256, 0, stream>>>((float4*)hist, HIST_PAD / 4);
  zero_kernel<<<1, 256, 0, stream>>>((float4*)nvalid, 1);
  zero_kernel<<<(N_EDGES * 2 / 4 + 255) / 256, 256, 0, stream>>>((float4*)einfo, N_EDGES * 2 / 4);
  hist_kernel<<<(N_EDGES + 255) / 256, 256, 0, stream>>>(ei, elen, hist, nvalid);
  scan_blocks_kernel<<<nb, 256, 0, stream>>>(hist, hist, bsums);
  scan_bsums_kernel<<<1, 256, 0, stream>>>(bsums, nb);
  scan_add_kernel<<<nb, 256, 0, stream>>>(hist, bsums, cursor);
  scatter_kernel<<<(N_EDGES + 255) / 256, 256, 0, stream>>>(ei, elen, cursor, perm, einfo);
  permute_ea_kernel<<<N_EDGES / 64, 256, 0, stream>>>(ea, perm, nvalid, eas);

  embed_kernel<<<(N_NODES * HID + 255) / 256, 256, 0, stream>>>(z, emblin_w, emblin_b, h);

  const int node_tiles = (N_NODES + 63) / 64;   // 782
  const int edge_tiles = N_EDGES / 64;          // 12500 (tail exits via nvalid)

  // x for block 0
  xgemm_kernel<<<node_tiles, 256, 0, stream>>>(h, wp_lin1, x);

  for (int i = 0; i < NBLK; i++) {
    zero_kernel<<<(N_NODES * NF / 4 + 255) / 256, 256, 0, stream>>>((float4*)agg, N_NODES * NF / 4);
    edge_kernel<<<edge_tiles, 256, 0, stream>>>(eas, einfo, nvalid,
        wp_nw1 + (size_t)i * FRAG_ELEMS, nn_b1 + (size_t)i * NF,
        wp_nw2 + (size_t)i * FRAG_ELEMS, nn_b2 + (size_t)i * NF,
        x, agg);
    node_kernel<<<node_tiles, 256, 0, stream>>>(agg,
        wp_l2 + (size_t)i * FRAG_ELEMS, lin2_b + (size_t)i * HID,
        wp_l + (size_t)i * FRAG_ELEMS, lin_b + (size_t)i * HID,
        (i + 1 < NBLK) ? (wp_lin1 + (size_t)(i + 1) * FRAG_ELEMS) : nullptr,
        h, x);
  }
}

// Round 2
// 1963.764 us; speedup vs baseline: 1.3171x; 1.0198x over previous
//
#include <hip/hip_runtime.h>
#include <cstddef>

typedef __bf16 bf16;
typedef bf16 bf16x4 __attribute__((ext_vector_type(4)));
typedef bf16 bf16x8 __attribute__((ext_vector_type(8)));
typedef float f32x4 __attribute__((ext_vector_type(4)));

#define N_NODES 50000
#define N_EDGES 800000
#define HID 128
#define NF 128
#define EC 100
#define NBLK 6
#define IN_DIM 5
#define LN2 0.69314718055994530942f
#define LDST 136          // bf16 LDS stride: 128 + 8 pad (16B-aligned rows, bank-skewed)
#define MST 136           // fp32 msg stride
#define EAS 112           // bf16 stride of pre-permuted edge_attr (cols 100..111 zero)
#define FRAG_ELEMS 16384  // one repacked 128x128 weight: 2048 frags x 8 bf16
#define HIST_PAD 50176    // 50000 rounded to 256*196, float4-zeroable

__device__ __forceinline__ float ssp_f(float v) {
  float e = __expf(-fabsf(v));
  return fmaxf(v, 0.0f) + __logf(1.0f + e) - LN2;
}

__device__ __forceinline__ f32x4 zero4() {
  f32x4 v; v[0] = 0.f; v[1] = 0.f; v[2] = 0.f; v[3] = 0.f; return v;
}

// ---------------- weight repack (once per launch) ----------------
__global__ void repack_kernel(const float* __restrict__ src, bf16* __restrict__ dst,
                              int K, int srcStride) {
  const int m = blockIdx.x;
  const float* s = src + (size_t)m * srcStride;
  bf16* d = dst + (size_t)m * FRAG_ELEMS;
  const int tid = threadIdx.x;
  const int wave = tid >> 6, lane = tid & 63;
  const int quad = lane >> 4, lanelo = lane & 15;
  const int col = wave * 32 + lanelo;
#pragma unroll
  for (int nt = 0; nt < 2; nt++)
#pragma unroll
    for (int ks = 0; ks < 4; ks++) {
      bf16x8 f;
#pragma unroll
      for (int j = 0; j < 8; j++) {
        int k = ks * 32 + quad * 8 + j;
        f[j] = (bf16)((k < K) ? s[(size_t)k * 128 + col + nt * 16] : 0.0f);
      }
      *(bf16x8*)&d[(size_t)(((wave * 2 + nt) * 4 + ks) * 64 + lane) * 8] = f;
    }
}

// ---------------- counting sort of VALID edges by dst (once per launch) ----------------
__global__ void hist_kernel(const int* __restrict__ ei, const float* __restrict__ elen,
                            int* __restrict__ hist, int* __restrict__ nvalid) {
  int e = blockIdx.x * 256 + threadIdx.x;
  if (e < N_EDGES) {
    float L = elen[e];
    if (L <= 10.0f && L >= 0.0f) {
      atomicAdd(&hist[ei[N_EDGES + e]], 1);
      atomicAdd(nvalid, 1);   // wave-coalesced by compiler
    }
  }
}

__global__ void scan_blocks_kernel(const int* __restrict__ in, int* __restrict__ out,
                                   int* __restrict__ bsums) {
  __shared__ int s[256];
  int i = blockIdx.x * 256 + threadIdx.x;
  int v = in[i];
  s[threadIdx.x] = v;
  __syncthreads();
#pragma unroll
  for (int off = 1; off < 256; off <<= 1) {
    int t = (threadIdx.x >= off) ? s[threadIdx.x - off] : 0;
    __syncthreads();
    s[threadIdx.x] += t;
    __syncthreads();
  }
  out[i] = s[threadIdx.x] - v;
  if (threadIdx.x == 255) bsums[blockIdx.x] = s[255];
}

__global__ void scan_bsums_kernel(int* __restrict__ bsums, int nb) {
  __shared__ int s[256];
  int v = (threadIdx.x < nb) ? bsums[threadIdx.x] : 0;
  s[threadIdx.x] = v;
  __syncthreads();
#pragma unroll
  for (int off = 1; off < 256; off <<= 1) {
    int t = (threadIdx.x >= off) ? s[threadIdx.x - off] : 0;
    __syncthreads();
    s[threadIdx.x] += t;
    __syncthreads();
  }
  if (threadIdx.x < nb) bsums[threadIdx.x] = s[threadIdx.x] - v;
}

__global__ void scan_add_kernel(int* __restrict__ out, const int* __restrict__ bsums,
                                int* __restrict__ cursor) {
  int i = blockIdx.x * 256 + threadIdx.x;
  int v = out[i] + bsums[blockIdx.x];
  out[i] = v;
  cursor[i] = v;
}

// scatter valid edges: rank[e] = sorted position (or -1); einfo[pos] = (src,dst)
__global__ void scatter_kernel(const int* __restrict__ ei, const float* __restrict__ elen,
                               int* __restrict__ cursor, int* __restrict__ rank,
                               int2* __restrict__ einfo) {
  int e = blockIdx.x * 256 + threadIdx.x;
  if (e < N_EDGES) {
    float L = elen[e];
    int rk = -1;
    if (L <= 10.0f && L >= 0.0f) {
      int s = ei[e];
      int d = ei[N_EDGES + e];
      rk = atomicAdd(&cursor[d], 1);
      einfo[rk] = make_int2(s, d);
    }
    rank[e] = rk;
  }
}

// ---------------- permute edge_attr into sorted bf16 stream (once per launch) ----------
// STREAMING read of ea (coalesced), scattered WRITE to eas[rank[e]] (fire-and-forget).
__global__ void permute_ea_kernel(const float* __restrict__ ea,
                                  const int* __restrict__ rank,
                                  bf16* __restrict__ eas) {
  __shared__ int s_rk[64];
  const int e0 = blockIdx.x * 64;
  const int tid = threadIdx.x;
  if (tid < 64) s_rk[tid] = rank[e0 + tid];
  __syncthreads();
#pragma unroll
  for (int it = 0; it < 4; it++) {
    int u = tid + it * 256;
    if (u < 64 * 14) {
      int r = u / 14, s = u - r * 14;
      int rk = s_rk[r];
      if (rk < 0) continue;
      const float* src = ea + (size_t)(e0 + r) * EC;  // rows are 16B-aligned (400 B)
      bf16x8 o;
#pragma unroll
      for (int j = 0; j < 8; j++) o[j] = (bf16)0.0f;
      if (s < 12) {
        float4 a = *(const float4*)&src[s * 8];
        float4 b = *(const float4*)&src[s * 8 + 4];
        o[0] = (bf16)a.x; o[1] = (bf16)a.y; o[2] = (bf16)a.z; o[3] = (bf16)a.w;
        o[4] = (bf16)b.x; o[5] = (bf16)b.y; o[6] = (bf16)b.z; o[7] = (bf16)b.w;
      } else if (s == 12) {
        float4 a = *(const float4*)&src[96];
        o[0] = (bf16)a.x; o[1] = (bf16)a.y; o[2] = (bf16)a.z; o[3] = (bf16)a.w;
      }
      *(bf16x8*)&eas[(size_t)rk * EAS + s * 8] = o;
    }
  }
}

// ---------------- misc ----------------
__global__ void zero_kernel(float4* __restrict__ p, int n4) {
  int i = blockIdx.x * 256 + threadIdx.x;
  if (i < n4) p[i] = make_float4(0.f, 0.f, 0.f, 0.f);
}

// ---------------- fused embed + x = h @ lin1 (block 0) ----------------
__global__ __launch_bounds__(256, 4)
void embed_xgemm_kernel(const float* __restrict__ z,
                        const float* __restrict__ ew,
                        const float* __restrict__ eb,
                        const bf16* __restrict__ wf,
                        float* __restrict__ h,
                        float* __restrict__ x) {
  __shared__ bf16 sA[64 * LDST];
  const int tid = threadIdx.x;
  const int wave = tid >> 6, lane = tid & 63;
  const int quad = lane >> 4, lanelo = lane & 15;
  const int ncol0 = wave * 32;
  const int row0 = blockIdx.x * 64;

  bf16x8 Bf[2][4];
#pragma unroll
  for (int nt = 0; nt < 2; nt++)
#pragma unroll
    for (int ks = 0; ks < 4; ks++)
      Bf[nt][ks] = *(const bf16x8*)&wf[(size_t)(((wave * 2 + nt) * 4 + ks) * 64 + lane) * 8];

#pragma unroll
  for (int it = 0; it < 8; it++) {
    int idx = tid + it * 256;
    int r = idx >> 5, c4 = idx & 31;
    int grow = row0 + r;
    float hv[4] = {0.f, 0.f, 0.f, 0.f};
    if (grow < N_NODES) {
      const float* zr = z + (size_t)grow * (IN_DIM + HID);
      float zf[IN_DIM];
#pragma unroll
      for (int k = 0; k < IN_DIM; k++) zf[k] = zr[k];
#pragma unroll
      for (int j = 0; j < 4; j++) {
        int c = c4 * 4 + j;
        float acc = eb[c] + zr[IN_DIM + c];
#pragma unroll
        for (int k = 0; k < IN_DIM; k++) acc = fmaf(zf[k], ew[k * HID + c], acc);
        hv[j] = acc;
        h[(size_t)grow * HID + c] = acc;
      }
    }
    bf16x4 o; o[0] = (bf16)hv[0]; o[1] = (bf16)hv[1]; o[2] = (bf16)hv[2]; o[3] = (bf16)hv[3];
    *(bf16x4*)&sA[r * LDST + c4 * 4] = o;
  }
  __syncthreads();

  f32x4 acc[4][2];
#pragma unroll
  for (int mt = 0; mt < 4; mt++)
#pragma unroll
    for (int nt = 0; nt < 2; nt++) acc[mt][nt] = zero4();
#pragma unroll
  for (int ks = 0; ks < 4; ks++) {
    bf16x8 a[4];
#pragma unroll
    for (int mt = 0; mt < 4; mt++)
      a[mt] = *(const bf16x8*)&sA[(mt * 16 + lanelo) * LDST + ks * 32 + quad * 8];
#pragma unroll
    for (int mt = 0; mt < 4; mt++)
#pragma unroll
      for (int nt = 0; nt < 2; nt++)
        acc[mt][nt] = __builtin_amdgcn_mfma_f32_16x16x32_bf16(a[mt], Bf[nt][ks], acc[mt][nt], 0, 0, 0);
  }
#pragma unroll
  for (int mt = 0; mt < 4; mt++)
#pragma unroll
    for (int r = 0; r < 4; r++) {
      int grow = row0 + mt * 16 + quad * 4 + r;
      if (grow < N_NODES) {
#pragma unroll
        for (int nt = 0; nt < 2; nt++)
          x[(size_t)grow * NF + ncol0 + nt * 16 + lanelo] = acc[mt][nt][r];
      }
    }
}

// ---------------- fused edge MLP + gather + segmented scatter-reduce ----------------
// ea pre-permuted+bf16 (streaming); x[src] prefetched into registers at entry so its
// L2/L3 latency hides under GEMM1+ssp+GEMM2 (T14 async-split).
__global__ __launch_bounds__(256, 4)
void edge_kernel(const bf16* __restrict__ eas,
                 const int2* __restrict__ einfo,
                 const int* __restrict__ nvalid,
                 const bf16* __restrict__ w1f, const float* __restrict__ b1,
                 const bf16* __restrict__ w2f, const float* __restrict__ b2,
                 const float* __restrict__ x,
                 float* __restrict__ agg) {
  __shared__ alignas(16) char s_buf[64 * MST * 4];  // 34816 B (bf16 GEMM tile / fp32 msg alias)
  bf16* sA = (bf16*)s_buf;
  float* s_msg = (float*)s_buf;
  __shared__ int s_dst[64];

  const int nv = *nvalid;
  const int e0 = blockIdx.x * 64;
  if (e0 >= nv) return;

  const int tid = threadIdx.x;
  const int wave = tid >> 6, lane = tid & 63;
  const int quad = lane >> 4, lanelo = lane & 15;
  const int ncol0 = wave * 32;

  // ---- early x-gather: issue before all GEMM work so latency hides under MFMA ----
  // Rows this thread owns in C-layout: mt*16 + quad*4 + r. Tail rows have einfo=(0,0)
  // (prefilled) -> safe address, masked to 0.
  float xg[4][4][2];
  bool vld[4][4];
#pragma unroll
  for (int mt = 0; mt < 4; mt++)
#pragma unroll
    for (int r = 0; r < 4; r++) {
      int row = mt * 16 + quad * 4 + r;
      int2 sd = einfo[e0 + row];
      bool v = (e0 + row) < nv;
      vld[mt][r] = v;
#pragma unroll
      for (int nt = 0; nt < 2; nt++) {
        float g = x[(size_t)sd.x * NF + ncol0 + nt * 16 + lanelo];
        xg[mt][r][nt] = v ? g : 0.0f;
      }
    }

  bf16x8 Bf1[2][4], Bf2[2][4];
#pragma unroll
  for (int nt = 0; nt < 2; nt++)
#pragma unroll
    for (int ks = 0; ks < 4; ks++) {
      size_t fo = (size_t)(((wave * 2 + nt) * 4 + ks) * 64 + lane) * 8;
      Bf1[nt][ks] = *(const bf16x8*)&w1f[fo];
      Bf2[nt][ks] = *(const bf16x8*)&w2f[fo];
    }
  float bias1[2], bias2[2];
#pragma unroll
  for (int nt = 0; nt < 2; nt++) {
    bias1[nt] = b1[ncol0 + nt * 16 + lanelo];
    bias2[nt] = b2[ncol0 + nt * 16 + lanelo];
  }

  // stage sorted ea tile: 64 rows x 17 segs of 8 bf16 (rows >= nv zero-filled here)
#pragma unroll
  for (int it = 0; it < 5; it++) {
    int u = tid + it * 256;
    if (u < 64 * 17) {
      int r = u / 17, s = u - r * 17;
      bf16x8 o;
      if (s < 14 && (e0 + r) < nv) {
        o = *(const bf16x8*)&eas[(size_t)(e0 + r) * EAS + s * 8];
      } else {
#pragma unroll
        for (int j = 0; j < 8; j++) o[j] = (bf16)0.0f;
      }
      *(bf16x8*)&sA[r * LDST + s * 8] = o;
    }
  }
  if (tid < 64) s_dst[tid] = einfo[e0 + tid].y;
  __syncthreads();

  // GEMM1: t = ea @ w1
  f32x4 acc[4][2];
#pragma unroll
  for (int mt = 0; mt < 4; mt++)
#pragma unroll
    for (int nt = 0; nt < 2; nt++) acc[mt][nt] = zero4();
#pragma unroll
  for (int ks = 0; ks < 4; ks++) {
    bf16x8 a[4];
#pragma unroll
    for (int mt = 0; mt < 4; mt++)
      a[mt] = *(const bf16x8*)&sA[(mt * 16 + lanelo) * LDST + ks * 32 + quad * 8];
#pragma unroll
    for (int mt = 0; mt < 4; mt++)
#pragma unroll
      for (int nt = 0; nt < 2; nt++)
        acc[mt][nt] = __builtin_amdgcn_mfma_f32_16x16x32_bf16(a[mt], Bf1[nt][ks], acc[mt][nt], 0, 0, 0);
  }
  __syncthreads();

  // ssp, C-layout -> A-layout, in place
#pragma unroll
  for (int mt = 0; mt < 4; mt++)
#pragma unroll
    for (int nt = 0; nt < 2; nt++)
#pragma unroll
      for (int r = 0; r < 4; r++) {
        float v = ssp_f(acc[mt][nt][r] + bias1[nt]);
        sA[(mt * 16 + quad * 4 + r) * LDST + ncol0 + nt * 16 + lanelo] = (bf16)v;
      }
  __syncthreads();

  // GEMM2: W = t @ w2
#pragma unroll
  for (int mt = 0; mt < 4; mt++)
#pragma unroll
    for (int nt = 0; nt < 2; nt++) acc[mt][nt] = zero4();
#pragma unroll
  for (int ks = 0; ks < 4; ks++) {
    bf16x8 a[4];
#pragma unroll
    for (int mt = 0; mt < 4; mt++)
      a[mt] = *(const bf16x8*)&sA[(mt * 16 + lanelo) * LDST + ks * 32 + quad * 8];
#pragma unroll
    for (int mt = 0; mt < 4; mt++)
#pragma unroll
      for (int nt = 0; nt < 2; nt++)
        acc[mt][nt] = __builtin_amdgcn_mfma_f32_16x16x32_bf16(a[mt], Bf2[nt][ks], acc[mt][nt], 0, 0, 0);
  }
  __syncthreads();  // all waves done with sA before fp32 msg overwrite (aliased)

  // msg = xg * W -> LDS (fp32); gathered values already resident in registers
#pragma unroll
  for (int mt = 0; mt < 4; mt++)
#pragma unroll
    for (int r = 0; r < 4; r++) {
      int row = mt * 16 + quad * 4 + r;
#pragma unroll
      for (int nt = 0; nt < 2; nt++) {
        int col = ncol0 + nt * 16 + lanelo;
        float wv = acc[mt][nt][r] + bias2[nt];
        s_msg[row * MST + col] = vld[mt][r] ? wv * xg[mt][r][nt] : 0.0f;
      }
    }
  __syncthreads();

  // segmented per-column reduction over dst-sorted rows
  {
    const int col = tid & 127;
    const int r0 = (tid >> 7) * 32;
    float acc2 = 0.0f;
    int prev = s_dst[r0];
    for (int r = r0; r < r0 + 32; r++) {
      int d = s_dst[r];
      if (d != prev) {
        atomicAdd(&agg[(size_t)prev * NF + col], acc2);
        acc2 = 0.0f;
        prev = d;
      }
      acc2 += s_msg[r * MST + col];
    }
    atomicAdd(&agg[(size_t)prev * NF + col], acc2);
  }
}

// ---------------- h += ssp(agg@lin2+b)@lin+b ; optionally x_next = h_new @ lin1_next ----
__global__ __launch_bounds__(256, 4)
void node_kernel(const float* __restrict__ agg,
                 const bf16* __restrict__ w1f, const float* __restrict__ b1,
                 const bf16* __restrict__ w2f, const float* __restrict__ b2,
                 const bf16* __restrict__ wxf,   // lin1 of next block, or null
                 float* __restrict__ h,
                 float* __restrict__ x) {
  __shared__ bf16 sA[64 * LDST];
  const int tid = threadIdx.x;
  const int wave = tid >> 6, lane = tid & 63;
  const int quad = lane >> 4, lanelo = lane & 15;
  const int ncol0 = wave * 32;
  const int row0 = blockIdx.x * 64;

  bf16x8 Bf1[2][4], Bf2[2][4];
#pragma unroll
  for (int nt = 0; nt < 2; nt++)
#pragma unroll
    for (int ks = 0; ks < 4; ks++) {
      size_t fo = (size_t)(((wave * 2 + nt) * 4 + ks) * 64 + lane) * 8;
      Bf1[nt][ks] = *(const bf16x8*)&w1f[fo];
      Bf2[nt][ks] = *(const bf16x8*)&w2f[fo];
    }
  float bias1[2], bias2[2];
#pragma unroll
  for (int nt = 0; nt < 2; nt++) {
    bias1[nt] = b1[ncol0 + nt * 16 + lanelo];
    bias2[nt] = b2[ncol0 + nt * 16 + lanelo];
  }

#pragma unroll
  for (int it = 0; it < 8; it++) {
    int idx = tid + it * 256;
    int r = idx >> 5, c4 = idx & 31;
    int grow = row0 + r;
    float4 v = (grow < N_NODES) ? *(const float4*)&agg[(size_t)grow * NF + c4 * 4]
                                : make_float4(0.f, 0.f, 0.f, 0.f);
    bf16x4 o; o[0] = (bf16)v.x; o[1] = (bf16)v.y; o[2] = (bf16)v.z; o[3] = (bf16)v.w;
    *(bf16x4*)&sA[r * LDST + c4 * 4] = o;
  }
  __syncthreads();

  f32x4 acc[4][2];
#pragma unroll
  for (int mt = 0; mt < 4; mt++)
#pragma unroll
    for (int nt = 0; nt < 2; nt++) acc[mt][nt] = zero4();
#pragma unroll
  for (int ks = 0; ks < 4; ks++) {
    bf16x8 a[4];
#pragma unroll
    for (int mt = 0; mt < 4; mt++)
      a[mt] = *(const bf16x8*)&sA[(mt * 16 + lanelo) * LDST + ks * 32 + quad * 8];
#pragma unroll
    for (int mt = 0; mt < 4; mt++)
#pragma unroll
      for (int nt = 0; nt < 2; nt++)
        acc[mt][nt] = __builtin_amdgcn_mfma_f32_16x16x32_bf16(a[mt], Bf1[nt][ks], acc[mt][nt], 0, 0, 0);
  }
  __syncthreads();

#pragma unroll
  for (int mt = 0; mt < 4; mt++)
#pragma unroll
    for (int nt = 0; nt < 2; nt++)
#pragma unroll
      for (int r = 0; r < 4; r++) {
        float v = ssp_f(acc[mt][nt][r] + bias1[nt]);
        sA[(mt * 16 + quad * 4 + r) * LDST + ncol0 + nt * 16 + lanelo] = (bf16)v;
      }
  __syncthreads();

#pragma unroll
  for (int mt = 0; mt < 4; mt++)
#pragma unroll
    for (int nt = 0; nt < 2; nt++) acc[mt][nt] = zero4();
#pragma unroll
  for (int ks = 0; ks < 4; ks++) {
    bf16x8 a[4];
#pragma unroll
    for (int mt = 0; mt < 4; mt++)
      a[mt] = *(const bf16x8*)&sA[(mt * 16 + lanelo) * LDST + ks * 32 + quad * 8];
#pragma unroll
    for (int mt = 0; mt < 4; mt++)
#pragma unroll
      for (int nt = 0; nt < 2; nt++)
        acc[mt][nt] = __builtin_amdgcn_mfma_f32_16x16x32_bf16(a[mt], Bf2[nt][ks], acc[mt][nt], 0, 0, 0);
  }
  __syncthreads();  // all GEMM2 LDS reads done before sA overwrite

  // h_new = h + acc + b2 -> global h; also stage h_new (bf16) for the fused x-GEMM
#pragma unroll
  for (int mt = 0; mt < 4; mt++)
#pragma unroll
    for (int nt = 0; nt < 2; nt++)
#pragma unroll
      for (int r = 0; r < 4; r++) {
        int row = mt * 16 + quad * 4 + r;
        int grow = row0 + row;
        int col = ncol0 + nt * 16 + lanelo;
        float hv = acc[mt][nt][r] + bias2[nt];
        if (grow < N_NODES) {
          size_t off = (size_t)grow * HID + col;
          hv += h[off];
          h[off] = hv;
        }
        sA[row * LDST + col] = (bf16)hv;
      }

  if (wxf != nullptr) {
    bf16x8 Bfx[2][4];
#pragma unroll
    for (int nt = 0; nt < 2; nt++)
#pragma unroll
      for (int ks = 0; ks < 4; ks++)
        Bfx[nt][ks] = *(const bf16x8*)&wxf[(size_t)(((wave * 2 + nt) * 4 + ks) * 64 + lane) * 8];
    __syncthreads();
#pragma unroll
    for (int mt = 0; mt < 4; mt++)
#pragma unroll
      for (int nt = 0; nt < 2; nt++) acc[mt][nt] = zero4();
#pragma unroll
    for (int ks = 0; ks < 4; ks++) {
      bf16x8 a[4];
#pragma unroll
      for (int mt = 0; mt < 4; mt++)
        a[mt] = *(const bf16x8*)&sA[(mt * 16 + lanelo) * LDST + ks * 32 + quad * 8];
#pragma unroll
      for (int mt = 0; mt < 4; mt++)
#pragma unroll
        for (int nt = 0; nt < 2; nt++)
          acc[mt][nt] = __builtin_amdgcn_mfma_f32_16x16x32_bf16(a[mt], Bfx[nt][ks], acc[mt][nt], 0, 0, 0);
    }
#pragma unroll
    for (int mt = 0; mt < 4; mt++)
#pragma unroll
      for (int r = 0; r < 4; r++) {
        int grow = row0 + mt * 16 + quad * 4 + r;
        if (grow < N_NODES) {
#pragma unroll
          for (int nt = 0; nt < 2; nt++)
            x[(size_t)grow * NF + ncol0 + nt * 16 + lanelo] = acc[mt][nt][r];
        }
      }
  }
}

extern "C" void kernel_launch(void* const* d_in, const int* in_sizes, int n_in,
                              void* d_out, int out_size, void* d_ws, size_t ws_size,
                              hipStream_t stream) {
  const float* z        = (const float*)d_in[0];
  const int*   ei       = (const int*)d_in[1];
  const float* elen     = (const float*)d_in[2];
  const float* ea       = (const float*)d_in[3];
  const float* emblin_w = (const float*)d_in[4];
  const float* emblin_b = (const float*)d_in[5];
  const float* lin1_w   = (const float*)d_in[6];
  const float* nn_w1    = (const float*)d_in[7];
  const float* nn_b1    = (const float*)d_in[8];
  const float* nn_w2    = (const float*)d_in[9];
  const float* nn_b2    = (const float*)d_in[10];
  const float* lin2_w   = (const float*)d_in[11];
  const float* lin2_b   = (const float*)d_in[12];
  const float* lin_w    = (const float*)d_in[13];
  const float* lin_b    = (const float*)d_in[14];

  float* h   = (float*)d_out;                        // 50000 x 128
  // ---- workspace layout (eas last; touched extent = nvalid rows) ----
  char* base = (char*)d_ws;
  float* x    = (float*)base;  base += (size_t)N_NODES * NF * 4;              // 25.6 MB
  float* agg  = (float*)base;  base += (size_t)N_NODES * NF * 4;              // 25.6 MB
  bf16* wp    = (bf16*)base;   base += (size_t)5 * NBLK * FRAG_ELEMS * 2;     // 0.98 MB
  int* hist   = (int*)base;    base += (size_t)HIST_PAD * 4;
  int* cursor = (int*)base;    base += (size_t)HIST_PAD * 4;
  int* bsums  = (int*)base;    base += 1024;
  int* nvalid = (int*)base;    base += 16;
  int* rank   = (int*)base;    base += (size_t)N_EDGES * 4;                   // 3.2 MB
  int2* einfo = (int2*)base;   base += (size_t)N_EDGES * 8;                   // 6.4 MB
  bf16* eas   = (bf16*)base;   base += (size_t)N_EDGES * EAS * 2;             // 179.2 MB

  bf16* wp_lin1 = wp;
  bf16* wp_nw1  = wp + 1 * (size_t)NBLK * FRAG_ELEMS;
  bf16* wp_nw2  = wp + 2 * (size_t)NBLK * FRAG_ELEMS;
  bf16* wp_l2   = wp + 3 * (size_t)NBLK * FRAG_ELEMS;
  bf16* wp_l    = wp + 4 * (size_t)NBLK * FRAG_ELEMS;

  // weight repack
  repack_kernel<<<NBLK, 256, 0, stream>>>(lin1_w, wp_lin1, HID, HID * NF);
  repack_kernel<<<NBLK, 256, 0, stream>>>(nn_w1, wp_nw1, EC, EC * NF);
  repack_kernel<<<NBLK, 256, 0, stream>>>(nn_w2, wp_nw2, NF, NF * NF);
  repack_kernel<<<NBLK, 256, 0, stream>>>(lin2_w, wp_l2, NF, NF * HID);
  repack_kernel<<<NBLK, 256, 0, stream>>>(lin_w, wp_l, HID, HID * HID);

  // counting sort of VALID edges by dst + sorted metadata + sorted bf16 edge_attr
  const int nb = HIST_PAD / 256;  // 196
  zero_kernel<<<(HIST_PAD / 4 + 255) / 256, 256, 0, stream>>>((float4*)hist, HIST_PAD / 4);
  zero_kernel<<<1, 256, 0, stream>>>((float4*)nvalid, 1);
  zero_kernel<<<(N_EDGES * 2 / 4 + 255) / 256, 256, 0, stream>>>((float4*)einfo, N_EDGES * 2 / 4);
  hist_kernel<<<(N_EDGES + 255) / 256, 256, 0, stream>>>(ei, elen, hist, nvalid);
  scan_blocks_kernel<<<nb, 256, 0, stream>>>(hist, hist, bsums);
  scan_bsums_kernel<<<1, 256, 0, stream>>>(bsums, nb);
  scan_add_kernel<<<nb, 256, 0, stream>>>(hist, bsums, cursor);
  scatter_kernel<<<(N_EDGES + 255) / 256, 256, 0, stream>>>(ei, elen, cursor, rank, einfo);
  permute_ea_kernel<<<N_EDGES / 64, 256, 0, stream>>>(ea, rank, eas);

  const int node_tiles = (N_NODES + 63) / 64;   // 782
  const int edge_tiles = N_EDGES / 64;          // 12500 (tail exits via nvalid)

  // h + x for block 0 (fused)
  embed_xgemm_kernel<<<node_tiles, 256, 0, stream>>>(z, emblin_w, emblin_b, wp_lin1, h, x);

  for (int i = 0; i < NBLK; i++) {
    zero_kernel<<<(N_NODES * NF / 4 + 255) / 256, 256, 0, stream>>>((float4*)agg, N_NODES * NF / 4);
    edge_kernel<<<edge_tiles, 256, 0, stream>>>(eas, einfo, nvalid,
        wp_nw1 + (size_t)i * FRAG_ELEMS, nn_b1 + (size_t)i * NF,
        wp_nw2 + (size_t)i * FRAG_ELEMS, nn_b2 + (size_t)i * NF,
        x, agg);
    node_kernel<<<node_tiles, 256, 0, stream>>>(agg,
        wp_l2 + (size_t)i * FRAG_ELEMS, lin2_b + (size_t)i * HID,
        wp_l + (size_t)i * FRAG_ELEMS, lin_b + (size_t)i * HID,
        (i + 1 < NBLK) ? (wp_lin1 + (size_t)(i + 1) * FRAG_ELEMS) : nullptr,
        h, x);
  }
}